// Round 4
// baseline (278.899 us; speedup 1.0000x reference)
//
#include <hip/hip_runtime.h>

#define BB 8
#define HH 512
#define WW 512
#define K2 9
#define HW (HH * WW)

// Tile geometry: each block computes a TY x TX pixel tile.
// LDS stages depth rows [ty0-5, ty0+TY+5] x cols [tx0-5, tx0+TX+5].
// Hot path is BRANCHLESS: samples come from the clamped LDS tile; a badmask
// records rare out-of-halo samples; a cold epilogue corrects them
// (subtract the deterministic wrong value, add the exact gsample value).
#define TX 64
#define TY 16
#define NROWS (TY + 11)   // 27
#define NCOLS (TX + 11)   // 75
#define STRIDE 77
#define NSTAGE 8          // ceil(NROWS*NCOLS / 256)
#define TILE_PAD (NROWS * STRIDE)   // dummy slot for branchless tail writes

// MISched fence: loads issued before this cannot be sunk past it, so the
// 27 upfront float4 loads stay grouped and the compiler emits its own
// counted vmcnt waits (27-deep MLP). No inline-asm loads -> no manual
// vmcnt bookkeeping, no early-clobber hazards, nothing can fault.
#define SFENCE() __builtin_amdgcn_sched_barrier(0)

// Reference clamp+mask bilinear from global (cold correction path only).
__device__ __forceinline__ float gsample(const float* __restrict__ dimg,
                                         float py, float px) {
    const float y0f = floorf(py);
    const float x0f = floorf(px);
    const float ty = py - y0f;
    const float tx = px - x0f;
    const int y0 = (int)y0f, x0 = (int)x0f;
    const int y1 = y0 + 1,   x1 = x0 + 1;
    const int y0c = min(max(y0, 0), HH - 1);
    const int y1c = min(max(y1, 0), HH - 1);
    const int x0c = min(max(x0, 0), WW - 1);
    const int x1c = min(max(x1, 0), WW - 1);
    const float v00 = dimg[y0c * WW + x0c];
    const float v01 = dimg[y0c * WW + x1c];
    const float v10 = dimg[y1c * WW + x0c];
    const float v11 = dimg[y1c * WW + x1c];
    const bool vy0 = (unsigned)y0 < HH, vy1 = (unsigned)y1 < HH;
    const bool vx0 = (unsigned)x0 < WW, vx1 = (unsigned)x1 < WW;
    const float w00 = (vy0 & vx0) ? (1.f - ty) * (1.f - tx) : 0.f;
    const float w01 = (vy0 & vx1) ? (1.f - ty) * tx         : 0.f;
    const float w10 = (vy1 & vx0) ? ty * (1.f - tx)         : 0.f;
    const float w11 = (vy1 & vx1) ? ty * tx                 : 0.f;
    return v00 * w00 + v01 * w01 + v10 * w10 + v11 * w11;
}

// Branchless sample: clamped-LDS bilinear + badmask bit. Wrong values for
// bad samples are deterministic and corrected in the cold epilogue.
// Tile contains zeros outside the image, so in-tile == reference semantics.
#define SAMPLE_BL(dyv, dxv, xoff, sj, KK, JJ)                               \
    do {                                                                    \
        const float py = (dyv) + ybase;                                     \
        const float px = (dxv) + xbase + (float)(xoff);                     \
        const float y0f = floorf(py);                                       \
        const float x0f = floorf(px);                                       \
        const float fty = py - y0f;                                         \
        const float ftx = px - x0f;                                         \
        const int iy = (int)y0f - ry0;                                      \
        const int ix = (int)x0f - cx0;                                      \
        const int iyc = min(max(iy, 0), NROWS - 2);                         \
        const int ixc = min(max(ix, 0), NCOLS - 2);                         \
        bad |= (unsigned long long)                                         \
               (((unsigned)iy >= NROWS - 1) | ((unsigned)ix >= NCOLS - 1))  \
               << ((KK) * 4 + (JJ));                                        \
        const float* q = tile + iyc * STRIDE + ixc;                         \
        const float v00 = q[0], v01 = q[1];                                 \
        const float v10 = q[STRIDE], v11 = q[STRIDE + 1];                   \
        const float a0 = v00 + ftx * (v01 - v00);                           \
        const float a1 = v10 + ftx * (v11 - v10);                           \
        sj = a0 + fty * (a1 - a0);                                          \
    } while (0)

#define DO_K(KK, w4, dy4, dx4)                                              \
    do {                                                                    \
        const float ybase = (float)(y - 1 + (KK) / 3);                      \
        const float xbase = (float)(x - 1 + (KK) % 3);                      \
        float s0, s1, s2, s3;                                               \
        SAMPLE_BL((dy4).x, (dx4).x, 0, s0, KK, 0);                          \
        SAMPLE_BL((dy4).y, (dx4).y, 1, s1, KK, 1);                          \
        SAMPLE_BL((dy4).z, (dx4).z, 2, s2, KK, 2);                          \
        SAMPLE_BL((dy4).w, (dx4).w, 3, s3, KK, 3);                          \
        accw.x += s0 * (w4).x;  accs.x += s0;  wsum.x += (w4).x;            \
        accw.y += s1 * (w4).y;  accs.y += s1;  wsum.y += (w4).y;            \
        accw.z += s2 * (w4).z;  accs.z += s2;  wsum.z += (w4).z;            \
        accw.w += s3 * (w4).w;  accs.w += s3;  wsum.w += (w4).w;            \
    } while (0)

// __launch_bounds__(256,3): 168-VGPR cap so the 27 in-flight float4 dsts
// (108 VGPRs) + accumulators fit WITHOUT spilling. 3 blocks/CU = 12
// waves/CU ~= the measured residency; the lever here is 27-deep MLP per
// wave, not TLP.
__global__ __launch_bounds__(256, 3) void pp_deconv_kernel(
    const float* __restrict__ depth,   // (B,1,H,W)
    const float* __restrict__ weight,  // (B,K2,H,W)
    const float* __restrict__ offset,  // (B,2*K2,H,W)
    float* __restrict__ out)           // (B,1,H,W)
{
    __shared__ float tile[NROWS * STRIDE + 1];   // +1 dummy slot

    const int tid = threadIdx.x;
    const int tx0 = blockIdx.x * TX;
    const int ty0 = blockIdx.y * TY;
    const int b   = blockIdx.z;

    const int ry0 = ty0 - 5;
    const int cx0 = tx0 - 5;

    const float* dimg = depth + (size_t)b * HW;

    // ---- staging: 8 guarded loads grouped (fence), then branchless LDS writes ----
    float sv[NSTAGE];
    int   sa[NSTAGE];
#pragma unroll
    for (int u = 0; u < NSTAGE; ++u) {
        const int li = tid + u * 256;
        const int r  = li / NCOLS;
        const int c  = li - r * NCOLS;
        const int gy = ry0 + r;
        const int gx = cx0 + c;
        float v = 0.f;
        if ((unsigned)gy < HH && (unsigned)gx < WW) v = dimg[gy * WW + gx];
        sv[u] = v;
        sa[u] = (li < NROWS * NCOLS) ? (r * STRIDE + c) : TILE_PAD;
    }
    SFENCE();   // keep the 8 staging loads issued before any ds_write waits
#pragma unroll
    for (int u = 0; u < NSTAGE; ++u) tile[sa[u]] = sv[u];   // no branch
    __syncthreads();   // standard barrier (drains vmcnt -- counts start clean)

    // ---- pixel mapping: 4 x-consecutive pixels per thread ----
    const int xl = (tid & 15) << 2;
    const int yl = tid >> 4;
    const int x = tx0 + xl;
    const int y = ty0 + yl;
    const int p = y * WW + x;

    const float* wp = weight + (size_t)b * K2 * HW + p;
    const float* op = offset + (size_t)b * 2 * K2 * HW + p;

    // ---- issue ALL 27 float4 loads upfront (plain C++), in consumption
    // order; the fence below stops the scheduler from sinking them. ----
    const float4 dy0 = *(const float4*)(op +  0 * HW);
    const float4 dx0 = *(const float4*)(op +  1 * HW);
    const float4 w0  = *(const float4*)(wp +  0 * HW);
    const float4 dy1 = *(const float4*)(op +  2 * HW);
    const float4 dx1 = *(const float4*)(op +  3 * HW);
    const float4 w1  = *(const float4*)(wp +  1 * HW);
    const float4 dy2 = *(const float4*)(op +  4 * HW);
    const float4 dx2 = *(const float4*)(op +  5 * HW);
    const float4 w2  = *(const float4*)(wp +  2 * HW);
    const float4 dy3 = *(const float4*)(op +  6 * HW);
    const float4 dx3 = *(const float4*)(op +  7 * HW);
    const float4 w3  = *(const float4*)(wp +  3 * HW);
    const float4 dy4 = *(const float4*)(op +  8 * HW);
    const float4 dx4 = *(const float4*)(op +  9 * HW);
    const float4 w4  = *(const float4*)(wp +  4 * HW);
    const float4 dy5 = *(const float4*)(op + 10 * HW);
    const float4 dx5 = *(const float4*)(op + 11 * HW);
    const float4 w5  = *(const float4*)(wp +  5 * HW);
    const float4 dy6 = *(const float4*)(op + 12 * HW);
    const float4 dx6 = *(const float4*)(op + 13 * HW);
    const float4 w6  = *(const float4*)(wp +  6 * HW);
    const float4 dy7 = *(const float4*)(op + 14 * HW);
    const float4 dx7 = *(const float4*)(op + 15 * HW);
    const float4 w7  = *(const float4*)(wp +  7 * HW);
    const float4 dy8 = *(const float4*)(op + 16 * HW);
    const float4 dx8 = *(const float4*)(op + 17 * HW);
    const float4 w8  = *(const float4*)(wp +  8 * HW);
    SFENCE();   // <-- loads pinned above; compiler emits counted vmcnt below

    float4 accw = make_float4(0.f, 0.f, 0.f, 0.f);
    float4 accs = make_float4(0.f, 0.f, 0.f, 0.f);
    float4 wsum = make_float4(0.f, 0.f, 0.f, 0.f);
    unsigned long long bad = 0ULL;

    DO_K(0, w0, dy0, dx0);
    DO_K(1, w1, dy1, dx1);
    DO_K(2, w2, dy2, dx2);
    DO_K(3, w3, dy3, dx3);
    DO_K(4, w4, dy4, dx4);
    DO_K(5, w5, dy5, dx5);
    DO_K(6, w6, dy6, dx6);
    DO_K(7, w7, dy7, dx7);
    DO_K(8, w8, dy8, dx8);

    // ---- cold correction for out-of-halo samples (P ~ 1e-4/sample) ----
    if (__builtin_expect(bad != 0ULL, 0)) {
#pragma unroll
        for (int j = 0; j < 4; ++j) {
            if (!((bad >> j) & 0x111111111ULL)) continue;
#pragma unroll 1
            for (int k = 0; k < K2; ++k) {
                if (!((bad >> (k * 4 + j)) & 1ULL)) continue;
                const float dyv = op[(2 * k) * HW + j];
                const float dxv = op[(2 * k + 1) * HW + j];
                const float wv  = wp[k * HW + j];
                const float ybase = (float)(y - 1 + k / 3);
                const float xbase = (float)(x - 1 + k % 3);
                const float py = dyv + ybase;
                const float px = dxv + xbase + (float)j;
                // recompute the wrong clamped-LDS value (deterministic)
                const float y0f = floorf(py), x0f = floorf(px);
                const float fty = py - y0f,  ftx = px - x0f;
                const int iy = (int)y0f - ry0, ix = (int)x0f - cx0;
                const int iyc = min(max(iy, 0), NROWS - 2);
                const int ixc = min(max(ix, 0), NCOLS - 2);
                const float* q = tile + iyc * STRIDE + ixc;
                const float a0 = q[0] + ftx * (q[1] - q[0]);
                const float a1 = q[STRIDE] + ftx * (q[STRIDE + 1] - q[STRIDE]);
                const float wrong = a0 + fty * (a1 - a0);
                const float d = gsample(dimg, py, px) - wrong;
                if (j == 0) { accw.x += d * wv; accs.x += d; }
                if (j == 1) { accw.y += d * wv; accs.y += d; }
                if (j == 2) { accw.z += d * wv; accs.z += d; }
                if (j == 3) { accw.w += d * wv; accs.w += d; }
            }
        }
    }

    // ---- epilogue: residual depth from LDS, store ----
    const float* dq = tile + (yl + 5) * STRIDE + (xl + 5);
    const float c9 = 1.0f / 9.0f;
    float4 o;
    o.x = accw.x - wsum.x * c9 * accs.x + dq[0];
    o.y = accw.y - wsum.y * c9 * accs.y + dq[1];
    o.z = accw.z - wsum.z * c9 * accs.z + dq[2];
    o.w = accw.w - wsum.w * c9 * accs.w + dq[3];
    *(float4*)(out + (size_t)b * HW + p) = o;
}

extern "C" void kernel_launch(void* const* d_in, const int* in_sizes, int n_in,
                              void* d_out, int out_size, void* d_ws, size_t ws_size,
                              hipStream_t stream) {
    const float* depth  = (const float*)d_in[0];
    const float* weight = (const float*)d_in[1];
    const float* offset = (const float*)d_in[2];
    float* out = (float*)d_out;

    dim3 grid(WW / TX, HH / TY, BB);   // 8 x 32 x 8 = 2048 blocks
    dim3 block(256);
    pp_deconv_kernel<<<grid, block, 0, stream>>>(depth, weight, offset, out);
}